// Round 2
// baseline (192.307 us; speedup 1.0000x reference)
//
#include <hip/hip_runtime.h>

// Edge (replicate) pad, width 2 on H and W.
// In:  (32, 256, 56, 56) fp32  -> NC = 8192 planes of 56x56
// Out: (32, 256, 60, 60) fp32
//
// One thread per output float4 (row = 60 floats = 15 float4).
// Interior float4s (w4=1..13) read a contiguous unaligned 4-float window
// with a single dwordx4 (4B alignment is sufficient for global_load_dwordx4
// on gfx9+). Edge float4s need only 2 scalar loads each:
//   w4=0  -> {s0,s0,s0,s1}
//   w4=14 -> {s54,s55,s55,s55}

#define IN_H  56
#define IN_W  56
#define OUT_H 60
#define OUT_W 60
#define PAD   2
#define W4    (OUT_W / 4)   // 15 float4 per output row

// 4-float vector with only 4-byte alignment requirement (unaligned load OK)
typedef float f4u __attribute__((ext_vector_type(4), aligned(4)));

__global__ __launch_bounds__(256) void pad2d_edge_kernel(
    const float* __restrict__ in, float* __restrict__ out, int n_vec) {
    int idx = blockIdx.x * blockDim.x + threadIdx.x;
    if (idx >= n_vec) return;

    int w4 = idx % W4;
    int t  = idx / W4;
    int oh = t % OUT_H;
    int nc = t / OUT_H;

    int ih = min(max(oh - PAD, 0), IN_H - 1);
    const float* src = in + (size_t)nc * (IN_H * IN_W) + (size_t)ih * IN_W;

    float4 v;
    if (w4 == 0) {
        float a = src[0];
        float b = src[1];
        v = make_float4(a, a, a, b);
    } else if (w4 == W4 - 1) {
        float a = src[IN_W - 2];
        float b = src[IN_W - 1];
        v = make_float4(a, b, b, b);
    } else {
        f4u u = *reinterpret_cast<const f4u*>(src + w4 * 4 - PAD);
        v = make_float4(u.x, u.y, u.z, u.w);
    }

    reinterpret_cast<float4*>(out)[idx] = v;
}

extern "C" void kernel_launch(void* const* d_in, const int* in_sizes, int n_in,
                              void* d_out, int out_size, void* d_ws, size_t ws_size,
                              hipStream_t stream) {
    const float* x = (const float*)d_in[0];
    float* out = (float*)d_out;

    int n_vec = out_size / 4;  // 32*256*60*60/4 = 7,372,800 threads
    int block = 256;
    int grid = (n_vec + block - 1) / block;
    pad2d_edge_kernel<<<grid, block, 0, stream>>>(x, out, n_vec);
}

// Round 4
// 187.829 us; speedup vs baseline: 1.0238x; 1.0238x over previous
//
#include <hip/hip_runtime.h>

// Edge (replicate) pad, width 2 on H and W.
// In:  (32, 256, 56, 56) fp32  -> NC = 8192 planes of 56x56
// Out: (32, 256, 60, 60) fp32
//
// One thread per output float4 (row = 60 floats = 15 float4).
// Wave-uniform memory: ALL lanes do one dwordx4 at a clamped window base,
// edge cases (w4=0 / w4=14) are fixed up with register permutes only —
// no loads under divergent control flow (1 load + 1 store per thread).
//   w4=0 : base=0,  window {s0..s3},   out {s0,s0,s0,s1}   = (x,x,x,y)
//   w4=14: base=52, window {s52..s55}, out {s54,s55,s55,s55} = (z,w,w,w)
//   else : base=ow0-2, identity

#define IN_H  56
#define IN_W  56
#define OUT_H 60
#define OUT_W 60
#define PAD   2
#define W4    (OUT_W / 4)   // 15 float4 per output row

// clang ext-vectors (usable with __builtin_nontemporal_store, unlike
// HIP's float4 class type). f4u = 4B-aligned for the unaligned source
// window; f4a = 16B-aligned for the output store.
typedef float f4u __attribute__((ext_vector_type(4), aligned(4)));
typedef float f4a __attribute__((ext_vector_type(4), aligned(16)));

__global__ __launch_bounds__(256) void pad2d_edge_kernel(
    const float* __restrict__ in, float* __restrict__ out, int n_vec) {
    int idx = blockIdx.x * blockDim.x + threadIdx.x;
    if (idx >= n_vec) return;

    int w4 = idx % W4;
    int t  = idx / W4;
    int oh = t % OUT_H;
    int nc = t / OUT_H;

    int ih = min(max(oh - PAD, 0), IN_H - 1);
    const float* src = in + (size_t)nc * (IN_H * IN_W) + (size_t)ih * IN_W;

    int ow0  = w4 * 4;
    int base = min(max(ow0 - PAD, 0), IN_W - 4);   // 0..52, always in-bounds
    f4u u = *reinterpret_cast<const f4u*>(src + base);

    // Register-only edge fixup (compiles to cndmasks, no divergent memory).
    f4a v;
    v.x = (w4 == W4 - 1) ? u.z : u.x;
    v.y = (w4 == 0)      ? u.x : ((w4 == W4 - 1) ? u.w : u.y);
    v.z = (w4 == 0)      ? u.x : ((w4 == W4 - 1) ? u.w : u.z);
    v.w = (w4 == 0)      ? u.y : ((w4 == W4 - 1) ? u.w : u.w);

    __builtin_nontemporal_store(v, reinterpret_cast<f4a*>(out) + idx);
}

extern "C" void kernel_launch(void* const* d_in, const int* in_sizes, int n_in,
                              void* d_out, int out_size, void* d_ws, size_t ws_size,
                              hipStream_t stream) {
    const float* x = (const float*)d_in[0];
    float* out = (float*)d_out;

    int n_vec = out_size / 4;  // 32*256*60*60/4 = 7,372,800 threads
    int block = 256;
    int grid = (n_vec + block - 1) / block;
    pad2d_edge_kernel<<<grid, block, 0, stream>>>(x, out, n_vec);
}